// Round 5
// baseline (857.209 us; speedup 1.0000x reference)
//
#include <hip/hip_runtime.h>

// FlowGuidedDCN: deformable 3x3 conv, stride=1, pad=1, dilation=1
// x: [B=8, C=3, H=512, W=512] f32 ; offsets: [B,18,H,W] f32 (dy,dx per tap)
// weight: [16,3,3,3] f32 ; bias: [16] f32 ; out: [B,16,H,W] f32

#define Bc 8
#define Cc 3
#define Hc 512
#define Wc 512
#define Oc 16
#define HWc (512 * 512)
#define KKc 9

// ---------- pass 1: x[B,C,H,W] -> xt[B,H,W,4] (channels-last, lane3=0) ----------
__global__ __launch_bounds__(256) void transpose_kernel(
    const float* __restrict__ x, float4* __restrict__ xt) {
  int pix = blockIdx.x * 256 + threadIdx.x;
  int b = pix >> 18;
  int hw = pix & (HWc - 1);
  const float* xb = x + b * (Cc * HWc) + hw;
  float4 v;
  v.x = xb[0];
  v.y = xb[HWc];
  v.z = xb[2 * HWc];
  v.w = 0.f;
  xt[pix] = v;
}

// ---------- pass 2: 4 pixels/thread, pipelined gathers ----------
// block = 128 threads = one image row; lane l owns w = l + p*128, p=0..3.
// Strided (not contiguous) pixel-per-thread mapping keeps every vmem
// instruction's 64 lanes contiguous in w -> same coalescing as 1px/thread,
// but 4x the independent loads in flight per wave.
__global__ __launch_bounds__(128, 2) void dcn_main4(
    const float4* __restrict__ xt,
    const float* __restrict__ offsets,
    const float* __restrict__ weight,
    const float* __restrict__ bias,
    float* __restrict__ out) {
  const int row = blockIdx.x;          // b*512 + h
  const int b = row >> 9;
  const int h = row & 511;
  const int l = threadIdx.x;           // 0..127

  const float4* __restrict__ xtb = xt + ((size_t)b << 18);
  const float* __restrict__ ob =
      offsets + (size_t)b * (2 * KKc * HWc) + (h << 9) + l;
  const float fh = (float)(h - 1);     // h - PAD

  float acc[Oc][4];
#pragma unroll
  for (int o = 0; o < Oc; ++o) {
    float bo = bias[o];
#pragma unroll
    for (int p = 0; p < 4; ++p) acc[o][p] = bo;
  }

  float oy[4], ox[4], oyN[4], oxN[4];
#pragma unroll
  for (int p = 0; p < 4; ++p) {
    oy[p] = __builtin_nontemporal_load(ob + 0 * HWc + (p << 7));
    ox[p] = __builtin_nontemporal_load(ob + 1 * HWc + (p << 7));
  }

#pragma unroll
  for (int kk = 0; kk < KKc; ++kk) {
    const int ky = kk / 3;
    const int kx = kk % 3;

    // prefetch next tap's offsets (independent of this tap's gathers)
    if (kk < KKc - 1) {
#pragma unroll
      for (int p = 0; p < 4; ++p) {
        oyN[p] = __builtin_nontemporal_load(ob + (2 * kk + 2) * HWc + (p << 7));
        oxN[p] = __builtin_nontemporal_load(ob + (2 * kk + 3) * HWc + (p << 7));
      }
    }

    float wt[4][4];
    int ad[4][4];
#pragma unroll
    for (int p = 0; p < 4; ++p) {
      float py = oy[p] + fh + (float)ky;
      float px = ox[p] + (float)(l + (p << 7) - 1 + kx);
      float y0f = floorf(py);
      float x0f = floorf(px);
      float wy = py - y0f;
      float wx = px - x0f;
      int y0 = (int)y0f;
      int x0 = (int)x0f;
      int y1 = y0 + 1;
      int x1 = x0 + 1;
      // validity folded into weights (factors exactly 0/1 == reference v*valid)
      float vy0 = ((unsigned)y0 < (unsigned)Hc) ? 1.f : 0.f;
      float vy1 = ((unsigned)y1 < (unsigned)Hc) ? 1.f : 0.f;
      float vx0 = ((unsigned)x0 < (unsigned)Wc) ? 1.f : 0.f;
      float vx1 = ((unsigned)x1 < (unsigned)Wc) ? 1.f : 0.f;
      float wy0 = 1.f - wy;
      float wx0 = 1.f - wx;
      wt[p][0] = (wy0 * wx0) * (vy0 * vx0);
      wt[p][1] = (wy0 * wx) * (vy0 * vx1);
      wt[p][2] = (wy * wx0) * (vy1 * vx0);
      wt[p][3] = (wy * wx) * (vy1 * vx1);
      int y0c = min(max(y0, 0), Hc - 1);
      int y1c = min(max(y1, 0), Hc - 1);
      int x0c = min(max(x0, 0), Wc - 1);
      int x1c = min(max(x1, 0), Wc - 1);
      ad[p][0] = (y0c << 9) + x0c;
      ad[p][1] = (y0c << 9) + x1c;
      ad[p][2] = (y1c << 9) + x0c;
      ad[p][3] = (y1c << 9) + x1c;
    }

    // batch-issue all 16 gathers for this tap
    float4 v[4][4];
#pragma unroll
    for (int p = 0; p < 4; ++p) {
      v[p][0] = xtb[ad[p][0]];
      v[p][1] = xtb[ad[p][1]];
      v[p][2] = xtb[ad[p][2]];
      v[p][3] = xtb[ad[p][3]];
    }
    // pin: gathers (and next-tap offset loads) issue BEFORE any consumption
    __builtin_amdgcn_sched_barrier(0);

#pragma unroll
    for (int p = 0; p < 4; ++p) {
      float w00 = wt[p][0], w01 = wt[p][1], w10 = wt[p][2], w11 = wt[p][3];
      float val0 = v[p][0].x * w00 + v[p][1].x * w01 + v[p][2].x * w10 + v[p][3].x * w11;
      float val1 = v[p][0].y * w00 + v[p][1].y * w01 + v[p][2].y * w10 + v[p][3].y * w11;
      float val2 = v[p][0].z * w00 + v[p][1].z * w01 + v[p][2].z * w10 + v[p][3].z * w11;
      const float* wk = weight + kk;  // compile-time offsets -> scalar K$ loads
#pragma unroll
      for (int o = 0; o < Oc; ++o) {
        acc[o][p] = fmaf(wk[o * 27 + 0], val0,
                    fmaf(wk[o * 27 + 9], val1,
                    fmaf(wk[o * 27 + 18], val2, acc[o][p])));
      }
    }

    if (kk < KKc - 1) {
#pragma unroll
      for (int p = 0; p < 4; ++p) { oy[p] = oyN[p]; ox[p] = oxN[p]; }
    }
  }

  float* op = out + (size_t)b * (Oc * HWc) + (h << 9) + l;
#pragma unroll
  for (int o = 0; o < Oc; ++o)
#pragma unroll
    for (int p = 0; p < 4; ++p)
      __builtin_nontemporal_store(acc[o][p], &op[o * HWc + (p << 7)]);
}

// ---------- fallback (ws too small): single-pass ----------
__global__ __launch_bounds__(256) void dcn_fallback(
    const float* __restrict__ x,
    const float* __restrict__ offsets,
    const float* __restrict__ weight,
    const float* __restrict__ bias,
    float* __restrict__ out) {
  int pix = blockIdx.x * 256 + threadIdx.x;
  int b = pix >> 18;
  int hw = pix & (HWc - 1);
  int h = hw >> 9;
  int w = hw & 511;
  const float* xb = x + b * (Cc * HWc);
  const float* ob = offsets + b * (2 * KKc * HWc) + hw;
  float acc[Oc];
#pragma unroll
  for (int o = 0; o < Oc; ++o) acc[o] = bias[o];
  const float fh = (float)(h - 1);
  const float fw = (float)(w - 1);
#pragma unroll
  for (int kk = 0; kk < KKc; ++kk) {
    const int ky = kk / 3, kx = kk % 3;
    float py = ob[(2 * kk) * HWc] + fh + (float)ky;
    float px = ob[(2 * kk + 1) * HWc] + fw + (float)kx;
    float y0f = floorf(py), x0f = floorf(px);
    float wy = py - y0f, wx = px - x0f;
    int y0 = (int)y0f, x0 = (int)x0f, y1 = y0 + 1, x1 = x0 + 1;
    float vy0 = ((unsigned)y0 < (unsigned)Hc) ? 1.f : 0.f;
    float vy1 = ((unsigned)y1 < (unsigned)Hc) ? 1.f : 0.f;
    float vx0 = ((unsigned)x0 < (unsigned)Wc) ? 1.f : 0.f;
    float vx1 = ((unsigned)x1 < (unsigned)Wc) ? 1.f : 0.f;
    float wy0 = 1.f - wy, wx0 = 1.f - wx;
    float w00 = (wy0 * wx0) * (vy0 * vx0);
    float w01 = (wy0 * wx) * (vy0 * vx1);
    float w10 = (wy * wx0) * (vy1 * vx0);
    float w11 = (wy * wx) * (vy1 * vx1);
    int y0c = min(max(y0, 0), Hc - 1);
    int y1c = min(max(y1, 0), Hc - 1);
    int x0c = min(max(x0, 0), Wc - 1);
    int x1c = min(max(x1, 0), Wc - 1);
    int a00 = (y0c << 9) + x0c, a01 = (y0c << 9) + x1c;
    int a10 = (y1c << 9) + x0c, a11 = (y1c << 9) + x1c;
    float val[Cc];
#pragma unroll
    for (int c = 0; c < Cc; ++c) {
      const float* xc = xb + c * HWc;
      val[c] = xc[a00] * w00 + xc[a01] * w01 + xc[a10] * w10 + xc[a11] * w11;
    }
    const float* wk = weight + kk;
#pragma unroll
    for (int o = 0; o < Oc; ++o)
#pragma unroll
      for (int c = 0; c < Cc; ++c)
        acc[o] = fmaf(wk[o * 27 + c * 9], val[c], acc[o]);
  }
  float* op = out + b * (Oc * HWc) + hw;
#pragma unroll
  for (int o = 0; o < Oc; ++o) op[o * HWc] = acc[o];
}

extern "C" void kernel_launch(void* const* d_in, const int* in_sizes, int n_in,
                              void* d_out, int out_size, void* d_ws, size_t ws_size,
                              hipStream_t stream) {
  const float* x = (const float*)d_in[0];
  const float* offsets = (const float*)d_in[1];
  const float* weight = (const float*)d_in[2];
  const float* bias = (const float*)d_in[3];
  float* out = (float*)d_out;

  const int total = Bc * HWc;
  const size_t xt_bytes = (size_t)total * 16;  // 32 MiB

  if (ws_size >= xt_bytes) {
    float4* xt = (float4*)d_ws;
    hipLaunchKernelGGL(transpose_kernel, dim3(total / 256), dim3(256), 0, stream, x, xt);
    hipLaunchKernelGGL(dcn_main4, dim3(Bc * Hc), dim3(128), 0, stream,
                       (const float4*)xt, offsets, weight, bias, out);
  } else {
    hipLaunchKernelGGL(dcn_fallback, dim3(total / 256), dim3(256), 0, stream,
                       x, offsets, weight, bias, out);
  }
}

// Round 6
// 392.144 us; speedup vs baseline: 2.1860x; 2.1860x over previous
//
#include <hip/hip_runtime.h>

// FlowGuidedDCN: deformable 3x3 conv, stride=1, pad=1, dilation=1
// x: [B=8, C=3, H=512, W=512] f32 ; offsets: [B,18,H,W] f32 (dy,dx per tap)
// weight: [16,3,3,3] f32 ; bias: [16] f32 ; out: [B,16,H,W] f32

#define Bc 8
#define Cc 3
#define Hc 512
#define Wc 512
#define Oc 16
#define HWc (512 * 512)
#define KKc 9

// ---------- pass 1: x[B,C,H,W] -> xt[B,H,W,4] (channels-last, lane3=0) ----------
__global__ __launch_bounds__(256) void transpose_kernel(
    const float* __restrict__ x, float4* __restrict__ xt) {
  int pix = blockIdx.x * 256 + threadIdx.x;
  int b = pix >> 18;
  int hw = pix & (HWc - 1);
  const float* xb = x + b * (Cc * HWc) + hw;
  float4 v;
  v.x = xb[0];
  v.y = xb[HWc];
  v.z = xb[2 * HWc];
  v.w = 0.f;
  xt[pix] = v;
}

// ---------- pass 2: 2 pixels/thread (w = l, l+256), one row per block ----------
// Live set budget (the R5 lesson): acc 32 + 8xfloat4 gathers 32 + wt/ad 16
// + offsets 8 + addressing ~20 ~= 110 VGPR -> fits 128, NO spills.
// No sched_barrier: the 8 gathers per tap are naturally independent.
__global__ __launch_bounds__(256, 2) void dcn_main2(
    const float4* __restrict__ xt,
    const float* __restrict__ offsets,
    const float* __restrict__ weight,
    const float* __restrict__ bias,
    float* __restrict__ out) {
  const int row = blockIdx.x;          // b*512 + h
  const int b = row >> 9;
  const int h = row & 511;
  const int l = threadIdx.x;           // 0..255

  const float4* __restrict__ xtb = xt + ((size_t)b << 18);
  const float* __restrict__ ob =
      offsets + (size_t)b * (2 * KKc * HWc) + (h << 9) + l;
  const float fh = (float)(h - 1);     // h - PAD

  float acc[Oc][2];
#pragma unroll
  for (int o = 0; o < Oc; ++o) {
    float bo = bias[o];
    acc[o][0] = bo;
    acc[o][1] = bo;
  }

  float oy[2], ox[2], oyN[2], oxN[2];
#pragma unroll
  for (int p = 0; p < 2; ++p) {
    oy[p] = __builtin_nontemporal_load(ob + 0 * HWc + (p << 8));
    ox[p] = __builtin_nontemporal_load(ob + 1 * HWc + (p << 8));
  }

#pragma unroll
  for (int kk = 0; kk < KKc; ++kk) {
    const int ky = kk / 3;
    const int kx = kk % 3;

    // prefetch next tap's offsets (independent of this tap's gathers)
    if (kk < KKc - 1) {
#pragma unroll
      for (int p = 0; p < 2; ++p) {
        oyN[p] = __builtin_nontemporal_load(ob + (2 * kk + 2) * HWc + (p << 8));
        oxN[p] = __builtin_nontemporal_load(ob + (2 * kk + 3) * HWc + (p << 8));
      }
    }

    float wt[2][4];
    int ad[2][4];
#pragma unroll
    for (int p = 0; p < 2; ++p) {
      float py = oy[p] + fh + (float)ky;
      float px = ox[p] + (float)(l + (p << 8) - 1 + kx);
      float y0f = floorf(py);
      float x0f = floorf(px);
      float wy = py - y0f;
      float wx = px - x0f;
      int y0 = (int)y0f;
      int x0 = (int)x0f;
      int y1 = y0 + 1;
      int x1 = x0 + 1;
      // validity folded into weights (factors exactly 0/1 == reference v*valid)
      float vy0 = ((unsigned)y0 < (unsigned)Hc) ? 1.f : 0.f;
      float vy1 = ((unsigned)y1 < (unsigned)Hc) ? 1.f : 0.f;
      float vx0 = ((unsigned)x0 < (unsigned)Wc) ? 1.f : 0.f;
      float vx1 = ((unsigned)x1 < (unsigned)Wc) ? 1.f : 0.f;
      float wy0 = 1.f - wy;
      float wx0 = 1.f - wx;
      wt[p][0] = (wy0 * wx0) * (vy0 * vx0);
      wt[p][1] = (wy0 * wx) * (vy0 * vx1);
      wt[p][2] = (wy * wx0) * (vy1 * vx0);
      wt[p][3] = (wy * wx) * (vy1 * vx1);
      int y0c = min(max(y0, 0), Hc - 1);
      int y1c = min(max(y1, 0), Hc - 1);
      int x0c = min(max(x0, 0), Wc - 1);
      int x1c = min(max(x1, 0), Wc - 1);
      ad[p][0] = (y0c << 9) + x0c;
      ad[p][1] = (y0c << 9) + x1c;
      ad[p][2] = (y1c << 9) + x0c;
      ad[p][3] = (y1c << 9) + x1c;
    }

    // 8 independent gathers for this tap (32 VGPRs in flight)
    float4 v[2][4];
#pragma unroll
    for (int p = 0; p < 2; ++p) {
      v[p][0] = xtb[ad[p][0]];
      v[p][1] = xtb[ad[p][1]];
      v[p][2] = xtb[ad[p][2]];
      v[p][3] = xtb[ad[p][3]];
    }

#pragma unroll
    for (int p = 0; p < 2; ++p) {
      float w00 = wt[p][0], w01 = wt[p][1], w10 = wt[p][2], w11 = wt[p][3];
      float val0 = v[p][0].x * w00 + v[p][1].x * w01 + v[p][2].x * w10 + v[p][3].x * w11;
      float val1 = v[p][0].y * w00 + v[p][1].y * w01 + v[p][2].y * w10 + v[p][3].y * w11;
      float val2 = v[p][0].z * w00 + v[p][1].z * w01 + v[p][2].z * w10 + v[p][3].z * w11;
      const float* wk = weight + kk;  // compile-time offsets -> scalar K$ loads
#pragma unroll
      for (int o = 0; o < Oc; ++o) {
        acc[o][p] = fmaf(wk[o * 27 + 0], val0,
                    fmaf(wk[o * 27 + 9], val1,
                    fmaf(wk[o * 27 + 18], val2, acc[o][p])));
      }
    }

    if (kk < KKc - 1) {
#pragma unroll
      for (int p = 0; p < 2; ++p) { oy[p] = oyN[p]; ox[p] = oxN[p]; }
    }
  }

  float* op = out + (size_t)b * (Oc * HWc) + (h << 9) + l;
#pragma unroll
  for (int o = 0; o < Oc; ++o)
#pragma unroll
    for (int p = 0; p < 2; ++p)
      __builtin_nontemporal_store(acc[o][p], &op[o * HWc + (p << 8)]);
}

// ---------- fallback (ws too small): single-pass ----------
__global__ __launch_bounds__(256) void dcn_fallback(
    const float* __restrict__ x,
    const float* __restrict__ offsets,
    const float* __restrict__ weight,
    const float* __restrict__ bias,
    float* __restrict__ out) {
  int pix = blockIdx.x * 256 + threadIdx.x;
  int b = pix >> 18;
  int hw = pix & (HWc - 1);
  int h = hw >> 9;
  int w = hw & 511;
  const float* xb = x + b * (Cc * HWc);
  const float* ob = offsets + b * (2 * KKc * HWc) + hw;
  float acc[Oc];
#pragma unroll
  for (int o = 0; o < Oc; ++o) acc[o] = bias[o];
  const float fh = (float)(h - 1);
  const float fw = (float)(w - 1);
#pragma unroll
  for (int kk = 0; kk < KKc; ++kk) {
    const int ky = kk / 3, kx = kk % 3;
    float py = ob[(2 * kk) * HWc] + fh + (float)ky;
    float px = ob[(2 * kk + 1) * HWc] + fw + (float)kx;
    float y0f = floorf(py), x0f = floorf(px);
    float wy = py - y0f, wx = px - x0f;
    int y0 = (int)y0f, x0 = (int)x0f, y1 = y0 + 1, x1 = x0 + 1;
    float vy0 = ((unsigned)y0 < (unsigned)Hc) ? 1.f : 0.f;
    float vy1 = ((unsigned)y1 < (unsigned)Hc) ? 1.f : 0.f;
    float vx0 = ((unsigned)x0 < (unsigned)Wc) ? 1.f : 0.f;
    float vx1 = ((unsigned)x1 < (unsigned)Wc) ? 1.f : 0.f;
    float wy0 = 1.f - wy, wx0 = 1.f - wx;
    float w00 = (wy0 * wx0) * (vy0 * vx0);
    float w01 = (wy0 * wx) * (vy0 * vx1);
    float w10 = (wy * wx0) * (vy1 * vx0);
    float w11 = (wy * wx) * (vy1 * vx1);
    int y0c = min(max(y0, 0), Hc - 1);
    int y1c = min(max(y1, 0), Hc - 1);
    int x0c = min(max(x0, 0), Wc - 1);
    int x1c = min(max(x1, 0), Wc - 1);
    int a00 = (y0c << 9) + x0c, a01 = (y0c << 9) + x1c;
    int a10 = (y1c << 9) + x0c, a11 = (y1c << 9) + x1c;
    float val[Cc];
#pragma unroll
    for (int c = 0; c < Cc; ++c) {
      const float* xc = xb + c * HWc;
      val[c] = xc[a00] * w00 + xc[a01] * w01 + xc[a10] * w10 + xc[a11] * w11;
    }
    const float* wk = weight + kk;
#pragma unroll
    for (int o = 0; o < Oc; ++o)
#pragma unroll
      for (int c = 0; c < Cc; ++c)
        acc[o] = fmaf(wk[o * 27 + c * 9], val[c], acc[o]);
  }
  float* op = out + b * (Oc * HWc) + hw;
#pragma unroll
  for (int o = 0; o < Oc; ++o) op[o * HWc] = acc[o];
}

extern "C" void kernel_launch(void* const* d_in, const int* in_sizes, int n_in,
                              void* d_out, int out_size, void* d_ws, size_t ws_size,
                              hipStream_t stream) {
  const float* x = (const float*)d_in[0];
  const float* offsets = (const float*)d_in[1];
  const float* weight = (const float*)d_in[2];
  const float* bias = (const float*)d_in[3];
  float* out = (float*)d_out;

  const int total = Bc * HWc;
  const size_t xt_bytes = (size_t)total * 16;  // 32 MiB

  if (ws_size >= xt_bytes) {
    float4* xt = (float4*)d_ws;
    hipLaunchKernelGGL(transpose_kernel, dim3(total / 256), dim3(256), 0, stream, x, xt);
    hipLaunchKernelGGL(dcn_main2, dim3(Bc * Hc), dim3(256), 0, stream,
                       (const float4*)xt, offsets, weight, bias, out);
  } else {
    hipLaunchKernelGGL(dcn_fallback, dim3(total / 256), dim3(256), 0, stream,
                       x, offsets, weight, bias, out);
  }
}

// Round 7
// 363.317 us; speedup vs baseline: 2.3594x; 1.0793x over previous
//
#include <hip/hip_runtime.h>

// FlowGuidedDCN: deformable 3x3 conv, stride=1, pad=1, dilation=1
// x: [B=8, C=3, H=512, W=512] f32 ; offsets: [B,18,H,W] f32 (dy,dx per tap)
// weight: [16,3,3,3] f32 ; bias: [16] f32 ; out: [B,16,H,W] f32

#define Bc 8
#define Cc 3
#define Hc 512
#define Wc 512
#define Oc 16
#define HWc (512 * 512)
#define KKc 9

// ---------- pass 1: x[B,C,H,W] -> xt[B,H,W,4] (channels-last, lane3=0) ----------
__global__ __launch_bounds__(256) void transpose_kernel(
    const float* __restrict__ x, float4* __restrict__ xt) {
  int pix = blockIdx.x * 256 + threadIdx.x;
  int b = pix >> 18;
  int hw = pix & (HWc - 1);
  const float* xb = x + b * (Cc * HWc) + hw;
  float4 v;
  v.x = xb[0];
  v.y = xb[HWc];
  v.z = xb[2 * HWc];
  v.w = 0.f;
  xt[pix] = v;
}

// ---------- pass 2: 1 px/thread, depth-1 pipelined taps, bounded liveness ----
// R5 lesson: pinning without register headroom spills (2.2 GB scratch).
// R3/R6 lesson: no pinning -> compiler sinks gathers, serializes 9 round trips.
// Here: liveness ~100 VGPR (off 18 + acc 16 + 2x4 float4 bufs 32 + misc),
// cap 128 via (256,2) -> pin is safe. Per tap the compiler emits a counted
// vmcnt wait (next tap's 4 gathers stay in flight across the consume).
__global__ __launch_bounds__(256, 2) void dcn_pipe(
    const float4* __restrict__ xt,
    const float* __restrict__ offsets,
    const float* __restrict__ weight,
    const float* __restrict__ bias,
    float* __restrict__ out) {
  const int pix = blockIdx.x * 256 + threadIdx.x;
  const int b = pix >> 18;
  const int hw = pix & (HWc - 1);
  const int h = hw >> 9;
  const int w = hw & 511;

  const float4* __restrict__ xtb = xt + ((size_t)b << 18);
  const float* __restrict__ ob = offsets + (size_t)b * (2 * KKc * HWc) + hw;
  const float fh = (float)(h - 1);  // h - PAD
  const float fw = (float)(w - 1);

  // burst-load all 18 offset planes (one waitcnt instead of 9 round trips)
  float off[2 * KKc];
#pragma unroll
  for (int i = 0; i < 2 * KKc; ++i)
    off[i] = __builtin_nontemporal_load(ob + i * HWc);

  float acc[Oc];
#pragma unroll
  for (int o = 0; o < Oc; ++o) acc[o] = bias[o];

  float4 vbuf[2][4];
  float wtb[2][4];

  // compute addr+weights for tap kk, issue its 4 gathers into slot s.
  // kk is a compile-time constant at every call site (full unroll).
  auto prep = [&](int kk, int s) {
    const int ky = kk / 3;
    const int kx = kk % 3;
    float py = off[2 * kk] + fh + (float)ky;
    float px = off[2 * kk + 1] + fw + (float)kx;
    float y0f = floorf(py);
    float x0f = floorf(px);
    float wy = py - y0f;
    float wx = px - x0f;
    int y0 = (int)y0f;
    int x0 = (int)x0f;
    int y1 = y0 + 1;
    int x1 = x0 + 1;
    // validity folded into weights (factors exactly 0/1 == reference v*valid)
    float vy0 = ((unsigned)y0 < (unsigned)Hc) ? 1.f : 0.f;
    float vy1 = ((unsigned)y1 < (unsigned)Hc) ? 1.f : 0.f;
    float vx0 = ((unsigned)x0 < (unsigned)Wc) ? 1.f : 0.f;
    float vx1 = ((unsigned)x1 < (unsigned)Wc) ? 1.f : 0.f;
    float wy0 = 1.f - wy;
    float wx0 = 1.f - wx;
    wtb[s][0] = (wy0 * wx0) * (vy0 * vx0);
    wtb[s][1] = (wy0 * wx) * (vy0 * vx1);
    wtb[s][2] = (wy * wx0) * (vy1 * vx0);
    wtb[s][3] = (wy * wx) * (vy1 * vx1);
    int y0c = min(max(y0, 0), Hc - 1);
    int y1c = min(max(y1, 0), Hc - 1);
    int x0c = min(max(x0, 0), Wc - 1);
    int x1c = min(max(x1, 0), Wc - 1);
    vbuf[s][0] = xtb[(y0c << 9) + x0c];
    vbuf[s][1] = xtb[(y0c << 9) + x1c];
    vbuf[s][2] = xtb[(y1c << 9) + x0c];
    vbuf[s][3] = xtb[(y1c << 9) + x1c];
  };

  prep(0, 0);

#pragma unroll
  for (int kk = 0; kk < KKc; ++kk) {
    const int cur = kk & 1;
    const int nxt = cur ^ 1;
    if (kk < KKc - 1) prep(kk + 1, nxt);
    // pin: next tap's gathers are issued BEFORE this tap's consume;
    // the consume's waitcnt is then counted (vmcnt(4)), not a full drain.
    __builtin_amdgcn_sched_barrier(0);

    float w00 = wtb[cur][0], w01 = wtb[cur][1];
    float w10 = wtb[cur][2], w11 = wtb[cur][3];
    float4 v00 = vbuf[cur][0], v01 = vbuf[cur][1];
    float4 v10 = vbuf[cur][2], v11 = vbuf[cur][3];
    float val0 = v00.x * w00 + v01.x * w01 + v10.x * w10 + v11.x * w11;
    float val1 = v00.y * w00 + v01.y * w01 + v10.y * w10 + v11.y * w11;
    float val2 = v00.z * w00 + v01.z * w01 + v10.z * w10 + v11.z * w11;

    const float* wk = weight + kk;  // compile-time offsets -> scalar K$ loads
#pragma unroll
    for (int o = 0; o < Oc; ++o) {
      acc[o] = fmaf(wk[o * 27 + 0], val0,
               fmaf(wk[o * 27 + 9], val1,
               fmaf(wk[o * 27 + 18], val2, acc[o])));
    }
  }

  float* op = out + (size_t)b * (Oc * HWc) + hw;
#pragma unroll
  for (int o = 0; o < Oc; ++o)
    __builtin_nontemporal_store(acc[o], &op[o * HWc]);
}

// ---------- fallback (ws too small): single-pass ----------
__global__ __launch_bounds__(256) void dcn_fallback(
    const float* __restrict__ x,
    const float* __restrict__ offsets,
    const float* __restrict__ weight,
    const float* __restrict__ bias,
    float* __restrict__ out) {
  int pix = blockIdx.x * 256 + threadIdx.x;
  int b = pix >> 18;
  int hw = pix & (HWc - 1);
  int h = hw >> 9;
  int w = hw & 511;
  const float* xb = x + b * (Cc * HWc);
  const float* ob = offsets + b * (2 * KKc * HWc) + hw;
  float acc[Oc];
#pragma unroll
  for (int o = 0; o < Oc; ++o) acc[o] = bias[o];
  const float fh = (float)(h - 1);
  const float fw = (float)(w - 1);
#pragma unroll
  for (int kk = 0; kk < KKc; ++kk) {
    const int ky = kk / 3, kx = kk % 3;
    float py = ob[(2 * kk) * HWc] + fh + (float)ky;
    float px = ob[(2 * kk + 1) * HWc] + fw + (float)kx;
    float y0f = floorf(py), x0f = floorf(px);
    float wy = py - y0f, wx = px - x0f;
    int y0 = (int)y0f, x0 = (int)x0f, y1 = y0 + 1, x1 = x0 + 1;
    float vy0 = ((unsigned)y0 < (unsigned)Hc) ? 1.f : 0.f;
    float vy1 = ((unsigned)y1 < (unsigned)Hc) ? 1.f : 0.f;
    float vx0 = ((unsigned)x0 < (unsigned)Wc) ? 1.f : 0.f;
    float vx1 = ((unsigned)x1 < (unsigned)Wc) ? 1.f : 0.f;
    float wy0 = 1.f - wy, wx0 = 1.f - wx;
    float w00 = (wy0 * wx0) * (vy0 * vx0);
    float w01 = (wy0 * wx) * (vy0 * vx1);
    float w10 = (wy * wx0) * (vy1 * vx0);
    float w11 = (wy * wx) * (vy1 * vx1);
    int y0c = min(max(y0, 0), Hc - 1);
    int y1c = min(max(y1, 0), Hc - 1);
    int x0c = min(max(x0, 0), Wc - 1);
    int x1c = min(max(x1, 0), Wc - 1);
    int a00 = (y0c << 9) + x0c, a01 = (y0c << 9) + x1c;
    int a10 = (y1c << 9) + x0c, a11 = (y1c << 9) + x1c;
    float val[Cc];
#pragma unroll
    for (int c = 0; c < Cc; ++c) {
      const float* xc = xb + c * HWc;
      val[c] = xc[a00] * w00 + xc[a01] * w01 + xc[a10] * w10 + xc[a11] * w11;
    }
    const float* wk = weight + kk;
#pragma unroll
    for (int o = 0; o < Oc; ++o)
#pragma unroll
      for (int c = 0; c < Cc; ++c)
        acc[o] = fmaf(wk[o * 27 + c * 9], val[c], acc[o]);
  }
  float* op = out + b * (Oc * HWc) + hw;
#pragma unroll
  for (int o = 0; o < Oc; ++o) op[o * HWc] = acc[o];
}

extern "C" void kernel_launch(void* const* d_in, const int* in_sizes, int n_in,
                              void* d_out, int out_size, void* d_ws, size_t ws_size,
                              hipStream_t stream) {
  const float* x = (const float*)d_in[0];
  const float* offsets = (const float*)d_in[1];
  const float* weight = (const float*)d_in[2];
  const float* bias = (const float*)d_in[3];
  float* out = (float*)d_out;

  const int total = Bc * HWc;
  const size_t xt_bytes = (size_t)total * 16;  // 32 MiB

  if (ws_size >= xt_bytes) {
    float4* xt = (float4*)d_ws;
    hipLaunchKernelGGL(transpose_kernel, dim3(total / 256), dim3(256), 0, stream, x, xt);
    hipLaunchKernelGGL(dcn_pipe, dim3(total / 256), dim3(256), 0, stream,
                       (const float4*)xt, offsets, weight, bias, out);
  } else {
    hipLaunchKernelGGL(dcn_fallback, dim3(total / 256), dim3(256), 0, stream,
                       x, offsets, weight, bias, out);
  }
}